// Round 4
// baseline (209.274 us; speedup 1.0000x reference)
//
#include <hip/hip_runtime.h>

// Problem constants (from reference setup_inputs)
#define N_PRE_C   50000
#define N_TYPES_C 20
#define N_BASIS_C 5
#define NB        2                     // batches
#define WORDS32   1568                  // ceil(50000/32)=1563, padded to 1568 (50176 bits)
#define MASK_U32  (WORDS32 * NB)        // 3136 u32 = 12544 B
#define UQ        4                     // quads (of 4 syn) per thread -> 16 syn/thread

typedef unsigned int u32;
typedef unsigned long long ull;

// ---------------------------------------------------------------------------
// Kernel 1: pack rec_z_buf (B x N_PRE floats, binary) into a u32 bitmask.
// Layout: mask[word][b] interleaved -> hit test reads 8B (ds_read_b64).
// ---------------------------------------------------------------------------
__global__ __launch_bounds__(256) void pack_spikes(const float* __restrict__ rec_z,
                                                   u32* __restrict__ mask) {
    const int b = blockIdx.y;
    const int i = blockIdx.x * 256 + threadIdx.x;   // [0, WORDS32*32)
    float v = 0.f;
    if (i < N_PRE_C) v = rec_z[b * N_PRE_C + i];
    ull m = __ballot(v > 0.f);
    const int l = threadIdx.x & 63;
    if ((l & 31) == 0)
        mask[(i >> 5) * NB + b] = (u32)(m >> (l & 32 ? 32 : 0));
}

// ---------------------------------------------------------------------------
// Per-synapse hit test + scatter into per-(b,post,TYPE) accumulator.
// 32-bit ops only; one fire-and-forget HW atomic per spike-hit.
// ---------------------------------------------------------------------------
__device__ __forceinline__ void proc1(int post, int pre, float w, int tt,
                                      const u32* __restrict__ sm,
                                      float* __restrict__ out_t, int n_post) {
    const u32 m0 = sm[(pre >> 5) * 2];
    const u32 m1 = sm[(pre >> 5) * 2 + 1];
    const u32 bit = 1u << (pre & 31);
    if (((m0 | m1) & bit) == 0u) return;            // ~96% early-out
    const int off = post * N_TYPES_C + tt;
    if (m0 & bit) unsafeAtomicAdd(out_t + off, w);
    if (m1 & bit) unsafeAtomicAdd(out_t + n_post * N_TYPES_C + off, w);
}

// ---------------------------------------------------------------------------
// Kernel 2: 16 syn/thread, wave-strided so every load is lane-contiguous.
// 16 independent vector loads in flight per thread before any use.
// ---------------------------------------------------------------------------
__global__ __launch_bounds__(256) void syn_scatter_t(
    const int4*  __restrict__ idx2,    // 2 synapses per int4 (post,pre,post,pre)
    const float4* __restrict__ w4,
    const int4*  __restrict__ sid4,
    const u32*   __restrict__ mask,
    float* __restrict__ out_t,         // [NB*n_post][N_TYPES] accumulator (zeroed)
    int n_post, int n_syn) {
    __shared__ __align__(16) u32 sm[MASK_U32];
    {   // stage mask with 16B loads
        const uint4* src = (const uint4*)mask;
        uint4* dst = (uint4*)sm;
        for (int t = threadIdx.x; t < MASK_U32 / 4; t += 256) dst[t] = src[t];
    }
    __syncthreads();

    const int  n_quads = n_syn >> 2;
    const long wave = ((long)blockIdx.x * 256 + threadIdx.x) >> 6;
    const int  lane = threadIdx.x & 63;
    const long q0   = wave * (64 * UQ) + lane;      // wave-strided quad indices

    int4 pa[UQ][2]; float4 wv[UQ]; int4 sv[UQ];
    #pragma unroll
    for (int u = 0; u < UQ; ++u) {
        const long q = q0 + u * 64;
        if (q < n_quads) {
            pa[u][0] = idx2[q * 2];
            pa[u][1] = idx2[q * 2 + 1];
            wv[u]    = w4[q];
            sv[u]    = sid4[q];
        }
    }
    #pragma unroll
    for (int u = 0; u < UQ; ++u) {
        const long q = q0 + u * 64;
        if (q < n_quads) {
            proc1(pa[u][0].x, pa[u][0].y, wv[u].x, sv[u].x, sm, out_t, n_post);
            proc1(pa[u][0].z, pa[u][0].w, wv[u].y, sv[u].y, sm, out_t, n_post);
            proc1(pa[u][1].x, pa[u][1].y, wv[u].z, sv[u].z, sm, out_t, n_post);
            proc1(pa[u][1].z, pa[u][1].w, wv[u].w, sv[u].w, sm, out_t, n_post);
        }
    }
    // leftover 0-3 synapses (n_syn % 4)
    if (blockIdx.x == 0 && threadIdx.x == 0) {
        const int*   idx = (const int*)idx2;
        const float* w   = (const float*)w4;
        const int*   sid = (const int*)sid4;
        for (long s = (long)n_quads * 4; s < n_syn; ++s)
            proc1(idx[2 * s], idx[2 * s + 1], w[s], sid[s], sm, out_t, n_post);
    }
}

// ---------------------------------------------------------------------------
// Kernel 3: combine out_t [rows][20] x basis [20][5] -> out [rows][5].
// ---------------------------------------------------------------------------
__global__ __launch_bounds__(256) void combine_basis(
    const float* __restrict__ out_t,
    const float* __restrict__ basis,   // [N_TYPES][N_BASIS]
    float* __restrict__ out, int rows) {
    __shared__ float sb[N_TYPES_C * N_BASIS_C];
    if (threadIdx.x < N_TYPES_C * N_BASIS_C) sb[threadIdx.x] = basis[threadIdx.x];
    __syncthreads();

    const int r = blockIdx.x * 256 + threadIdx.x;
    if (r >= rows) return;
    const float4* p = (const float4*)(out_t + (long)r * N_TYPES_C);
    float4 v0 = p[0], v1 = p[1], v2 = p[2], v3 = p[3], v4 = p[4];
    float vt[N_TYPES_C] = {v0.x, v0.y, v0.z, v0.w, v1.x, v1.y, v1.z, v1.w,
                           v2.x, v2.y, v2.z, v2.w, v3.x, v3.y, v3.z, v3.w,
                           v4.x, v4.y, v4.z, v4.w};
    float acc[N_BASIS_C] = {0.f, 0.f, 0.f, 0.f, 0.f};
    #pragma unroll
    for (int t = 0; t < N_TYPES_C; ++t) {
        #pragma unroll
        for (int k = 0; k < N_BASIS_C; ++k)
            acc[k] += vt[t] * sb[t * N_BASIS_C + k];   // sb read is a broadcast
    }
    float* o = out + (long)r * N_BASIS_C;
    #pragma unroll
    for (int k = 0; k < N_BASIS_C; ++k) o[k] = acc[k];
}

// ---------------------------------------------------------------------------
// Fallback (only if ws too small): direct 5-atomic scatter into out.
// ---------------------------------------------------------------------------
__device__ __forceinline__ void proc_direct(int post, int pre, float wv, int tt,
                                            const u32* __restrict__ sm,
                                            const float (*sb)[N_BASIS_C],
                                            float* __restrict__ out, int n_post) {
    const u32 m0 = sm[(pre >> 5) * 2];
    const u32 m1 = sm[(pre >> 5) * 2 + 1];
    const u32 bit = 1u << (pre & 31);
    if (((m0 | m1) & bit) == 0u) return;
    const float* bs = sb[tt];
    float c[N_BASIS_C];
    #pragma unroll
    for (int k = 0; k < N_BASIS_C; ++k) c[k] = wv * bs[k];
    if (m0 & bit) {
        float* o = out + (long)post * N_BASIS_C;
        #pragma unroll
        for (int k = 0; k < N_BASIS_C; ++k) unsafeAtomicAdd(o + k, c[k]);
    }
    if (m1 & bit) {
        float* o = out + (long)(n_post + post) * N_BASIS_C;
        #pragma unroll
        for (int k = 0; k < N_BASIS_C; ++k) unsafeAtomicAdd(o + k, c[k]);
    }
}

__global__ __launch_bounds__(256) void syn_scatter_direct(
    const int4* __restrict__ idx2, const float4* __restrict__ w4,
    const int4* __restrict__ sid4, const float* __restrict__ basis,
    const u32* __restrict__ mask, float* __restrict__ out,
    int n_post, int n_syn) {
    __shared__ __align__(16) u32 sm[MASK_U32];
    __shared__ float sb[N_TYPES_C][N_BASIS_C];
    for (int t = threadIdx.x; t < MASK_U32; t += 256) sm[t] = mask[t];
    for (int t = threadIdx.x; t < N_TYPES_C * N_BASIS_C; t += 256)
        ((float*)sb)[t] = basis[t];
    __syncthreads();
    const int t = blockIdx.x * 256 + threadIdx.x;
    const long base = (long)t * 4;
    if (base >= n_syn) return;
    if (base + 4 <= n_syn) {
        const int4   p01 = idx2[(long)t * 2];
        const int4   p23 = idx2[(long)t * 2 + 1];
        const float4 wv  = w4[t];
        const int4   sv  = sid4[t];
        proc_direct(p01.x, p01.y, wv.x, sv.x, sm, sb, out, n_post);
        proc_direct(p01.z, p01.w, wv.y, sv.y, sm, sb, out, n_post);
        proc_direct(p23.x, p23.y, wv.z, sv.z, sm, sb, out, n_post);
        proc_direct(p23.z, p23.w, wv.w, sv.w, sm, sb, out, n_post);
    } else {
        const int*   idx = (const int*)idx2;
        const float* w   = (const float*)w4;
        const int*   sid = (const int*)sid4;
        for (long s = base; s < n_syn; ++s)
            proc_direct(idx[2 * s], idx[2 * s + 1], w[s], sid[s], sm, sb, out, n_post);
    }
}

extern "C" void kernel_launch(void* const* d_in, const int* in_sizes, int n_in,
                              void* d_out, int out_size, void* d_ws, size_t ws_size,
                              hipStream_t stream) {
    const float* rec_z   = (const float*)d_in[0];
    const float* weights = (const float*)d_in[1];
    const float* basis   = (const float*)d_in[2];
    const int*   synidx  = (const int*)d_in[3];
    const int*   synids  = (const int*)d_in[4];
    float*       out     = (float*)d_out;

    const int n_syn  = in_sizes[4];
    const int rows   = out_size / N_BASIS_C;       // NB * n_post
    const int n_post = rows / NB;
    const int n_quads = n_syn >> 2;

    // Workspace layout: out_t [rows][N_TYPES] floats, then mask.
    const size_t out_t_bytes = (size_t)rows * N_TYPES_C * sizeof(float);
    const size_t mask_bytes  = (size_t)MASK_U32 * sizeof(u32);

    if (ws_size >= out_t_bytes + mask_bytes) {
        float* out_t = (float*)d_ws;
        u32*   mask  = (u32*)((char*)d_ws + out_t_bytes);

        hipMemsetAsync(out_t, 0, out_t_bytes, stream);
        pack_spikes<<<dim3(WORDS32 * 32 / 256, NB), 256, 0, stream>>>(rec_z, mask);

        // 16 syn per thread: blocks = ceil(n_quads / (UQ*256))
        const int blocks = (n_quads + UQ * 256 - 1) / (UQ * 256);
        syn_scatter_t<<<(blocks > 0 ? blocks : 1), 256, 0, stream>>>(
            (const int4*)synidx, (const float4*)weights, (const int4*)synids,
            mask, out_t, n_post, n_syn);
        combine_basis<<<(rows + 255) / 256, 256, 0, stream>>>(out_t, basis, out, rows);
    } else {
        // Fallback: direct 5-atomic scatter.
        u32* mask = (u32*)d_ws;
        hipMemsetAsync(d_out, 0, (size_t)out_size * sizeof(float), stream);
        pack_spikes<<<dim3(WORDS32 * 32 / 256, NB), 256, 0, stream>>>(rec_z, mask);
        const int n_thr  = (n_syn + 3) / 4;
        syn_scatter_direct<<<(n_thr + 255) / 256, 256, 0, stream>>>(
            (const int4*)synidx, (const float4*)weights, (const int4*)synids,
            basis, mask, out, n_post, n_syn);
    }
}

// Round 5
// 201.642 us; speedup vs baseline: 1.0378x; 1.0378x over previous
//
#include <hip/hip_runtime.h>

// Problem constants (from reference setup_inputs)
#define N_PRE_C   50000
#define N_TYPES_C 20
#define N_BASIS_C 5
#define NB        2                    // batches
#define WORDS     784                  // ceil(50000/64)=782, padded to 784

typedef unsigned long long ull;

// ---------------------------------------------------------------------------
// Kernel 1: pack rec_z_buf (B x N_PRE floats, binary) into a u64 bitmask.
// Layout: mask[word][b] interleaved; the (b0,b1) pair is 16B-aligned so the
// scatter kernel's hit test is ONE global_load_dwordx4 (L1-resident, 12.5 KB).
// ---------------------------------------------------------------------------
__global__ __launch_bounds__(256) void pack_spikes(const float* __restrict__ rec_z,
                                                   ull* __restrict__ mask) {
    const int b = blockIdx.y;
    const int i = blockIdx.x * 256 + threadIdx.x;   // [0, WORDS*64)
    float v = 0.f;
    if (i < N_PRE_C) v = rec_z[b * N_PRE_C + i];
    ull m = __ballot(v > 0.f);
    if ((threadIdx.x & 63) == 0) mask[(i >> 6) * NB + b] = m;
}

// ---------------------------------------------------------------------------
// Per-synapse hit test (direct L1 mask read) + scatter into per-(b,post,TYPE)
// accumulator. One fire-and-forget HW atomic per spike-hit.
// ---------------------------------------------------------------------------
__device__ __forceinline__ void proc1(int post, int pre, float w, int tt,
                                      const ulonglong2* __restrict__ mask2,
                                      float* __restrict__ out_t,
                                      float* __restrict__ out_t_b1) {
    const ulonglong2 m = mask2[pre >> 6];           // 16B load, L1-hot (12.5 KB)
    const ull bit = 1ull << (pre & 63);
    if (((m.x | m.y) & bit) == 0ull) return;        // ~96% early-out
    const int off = post * N_TYPES_C + tt;
    if (m.x & bit) unsafeAtomicAdd(out_t + off, w);
    if (m.y & bit) unsafeAtomicAdd(out_t_b1 + off, w);
}

// ---------------------------------------------------------------------------
// Kernel 2: 4 syn/thread, one-shot mapping, no LDS, no barrier.
// ---------------------------------------------------------------------------
__global__ __launch_bounds__(256) void syn_scatter_t(
    const int4*  __restrict__ idx2,    // 2 synapses per int4 (post,pre,post,pre)
    const float4* __restrict__ w4,
    const int4*  __restrict__ sid4,
    const ulonglong2* __restrict__ mask2,
    float* __restrict__ out_t,         // [NB*n_post][N_TYPES] accumulator (zeroed)
    int n_post, int n_syn) {
    const int t = blockIdx.x * 256 + threadIdx.x;
    const long base = (long)t * 4;
    if (base >= n_syn) return;

    float* out_t_b1 = out_t + (long)n_post * N_TYPES_C;

    if (base + 4 <= n_syn) {
        // Coalesced stream loads: 32B idx + 16B w + 16B sid per lane.
        const int4   p01 = idx2[(long)t * 2];
        const int4   p23 = idx2[(long)t * 2 + 1];
        const float4 wv  = w4[t];
        const int4   sv  = sid4[t];
        proc1(p01.x, p01.y, wv.x, sv.x, mask2, out_t, out_t_b1);
        proc1(p01.z, p01.w, wv.y, sv.y, mask2, out_t, out_t_b1);
        proc1(p23.x, p23.y, wv.z, sv.z, mask2, out_t, out_t_b1);
        proc1(p23.z, p23.w, wv.w, sv.w, mask2, out_t, out_t_b1);
    } else {
        const int*   idx = (const int*)idx2;
        const float* w   = (const float*)w4;
        const int*   sid = (const int*)sid4;
        for (long s = base; s < n_syn; ++s)
            proc1(idx[2 * s], idx[2 * s + 1], w[s], sid[s], mask2, out_t, out_t_b1);
    }
}

// ---------------------------------------------------------------------------
// Kernel 3: combine out_t [rows][20] x basis [20][5] -> out [rows][5].
// ---------------------------------------------------------------------------
__global__ __launch_bounds__(256) void combine_basis(
    const float* __restrict__ out_t,
    const float* __restrict__ basis,   // [N_TYPES][N_BASIS]
    float* __restrict__ out, int rows) {
    __shared__ float sb[N_TYPES_C * N_BASIS_C];
    if (threadIdx.x < N_TYPES_C * N_BASIS_C) sb[threadIdx.x] = basis[threadIdx.x];
    __syncthreads();

    const int r = blockIdx.x * 256 + threadIdx.x;
    if (r >= rows) return;
    const float4* p = (const float4*)(out_t + (long)r * N_TYPES_C);
    float4 v0 = p[0], v1 = p[1], v2 = p[2], v3 = p[3], v4 = p[4];
    float vt[N_TYPES_C] = {v0.x, v0.y, v0.z, v0.w, v1.x, v1.y, v1.z, v1.w,
                           v2.x, v2.y, v2.z, v2.w, v3.x, v3.y, v3.z, v3.w,
                           v4.x, v4.y, v4.z, v4.w};
    float acc[N_BASIS_C] = {0.f, 0.f, 0.f, 0.f, 0.f};
    #pragma unroll
    for (int t = 0; t < N_TYPES_C; ++t) {
        #pragma unroll
        for (int k = 0; k < N_BASIS_C; ++k)
            acc[k] += vt[t] * sb[t * N_BASIS_C + k];   // sb read is a broadcast
    }
    float* o = out + (long)r * N_BASIS_C;
    #pragma unroll
    for (int k = 0; k < N_BASIS_C; ++k) o[k] = acc[k];
}

// ---------------------------------------------------------------------------
// Fallback (only if ws too small): direct 5-atomic scatter into out.
// ---------------------------------------------------------------------------
__device__ __forceinline__ void proc_direct(int post, int pre, float wv, int tt,
                                            const ulonglong2* __restrict__ mask2,
                                            const float (*sb)[N_BASIS_C],
                                            float* __restrict__ out, int n_post) {
    const ulonglong2 m = mask2[pre >> 6];
    const ull bit = 1ull << (pre & 63);
    if (((m.x | m.y) & bit) == 0ull) return;
    const float* bs = sb[tt];
    float c[N_BASIS_C];
    #pragma unroll
    for (int k = 0; k < N_BASIS_C; ++k) c[k] = wv * bs[k];
    if (m.x & bit) {
        float* o = out + (long)post * N_BASIS_C;
        #pragma unroll
        for (int k = 0; k < N_BASIS_C; ++k) unsafeAtomicAdd(o + k, c[k]);
    }
    if (m.y & bit) {
        float* o = out + (long)(n_post + post) * N_BASIS_C;
        #pragma unroll
        for (int k = 0; k < N_BASIS_C; ++k) unsafeAtomicAdd(o + k, c[k]);
    }
}

__global__ __launch_bounds__(256) void syn_scatter_direct(
    const int4* __restrict__ idx2, const float4* __restrict__ w4,
    const int4* __restrict__ sid4, const float* __restrict__ basis,
    const ulonglong2* __restrict__ mask2, float* __restrict__ out,
    int n_post, int n_syn) {
    __shared__ float sb[N_TYPES_C][N_BASIS_C];
    for (int t = threadIdx.x; t < N_TYPES_C * N_BASIS_C; t += 256)
        ((float*)sb)[t] = basis[t];
    __syncthreads();
    const int t = blockIdx.x * 256 + threadIdx.x;
    const long base = (long)t * 4;
    if (base >= n_syn) return;
    if (base + 4 <= n_syn) {
        const int4   p01 = idx2[(long)t * 2];
        const int4   p23 = idx2[(long)t * 2 + 1];
        const float4 wv  = w4[t];
        const int4   sv  = sid4[t];
        proc_direct(p01.x, p01.y, wv.x, sv.x, mask2, sb, out, n_post);
        proc_direct(p01.z, p01.w, wv.y, sv.y, mask2, sb, out, n_post);
        proc_direct(p23.x, p23.y, wv.z, sv.z, mask2, sb, out, n_post);
        proc_direct(p23.z, p23.w, wv.w, sv.w, mask2, sb, out, n_post);
    } else {
        const int*   idx = (const int*)idx2;
        const float* w   = (const float*)w4;
        const int*   sid = (const int*)sid4;
        for (long s = base; s < n_syn; ++s)
            proc_direct(idx[2 * s], idx[2 * s + 1], w[s], sid[s], mask2, sb, out, n_post);
    }
}

extern "C" void kernel_launch(void* const* d_in, const int* in_sizes, int n_in,
                              void* d_out, int out_size, void* d_ws, size_t ws_size,
                              hipStream_t stream) {
    const float* rec_z   = (const float*)d_in[0];
    const float* weights = (const float*)d_in[1];
    const float* basis   = (const float*)d_in[2];
    const int*   synidx  = (const int*)d_in[3];
    const int*   synids  = (const int*)d_in[4];
    float*       out     = (float*)d_out;

    const int n_syn  = in_sizes[4];
    const int rows   = out_size / N_BASIS_C;       // NB * n_post
    const int n_post = rows / NB;
    const int n_thr  = (n_syn + 3) / 4;
    const int blocks = (n_thr + 255) / 256;        // one-shot mapping

    // Workspace layout: out_t [rows][N_TYPES] floats, then mask (16B aligned).
    const size_t out_t_bytes = (size_t)rows * N_TYPES_C * sizeof(float);
    const size_t mask_bytes  = (size_t)WORDS * NB * sizeof(ull);

    if (ws_size >= out_t_bytes + mask_bytes) {
        float* out_t = (float*)d_ws;
        ull*   mask  = (ull*)((char*)d_ws + out_t_bytes);

        hipMemsetAsync(out_t, 0, out_t_bytes, stream);
        pack_spikes<<<dim3(WORDS * 64 / 256, NB), 256, 0, stream>>>(rec_z, mask);
        syn_scatter_t<<<blocks, 256, 0, stream>>>(
            (const int4*)synidx, (const float4*)weights, (const int4*)synids,
            (const ulonglong2*)mask, out_t, n_post, n_syn);
        combine_basis<<<(rows + 255) / 256, 256, 0, stream>>>(out_t, basis, out, rows);
    } else {
        // Fallback: direct 5-atomic scatter.
        ull* mask = (ull*)d_ws;
        hipMemsetAsync(d_out, 0, (size_t)out_size * sizeof(float), stream);
        pack_spikes<<<dim3(WORDS * 64 / 256, NB), 256, 0, stream>>>(rec_z, mask);
        syn_scatter_direct<<<blocks, 256, 0, stream>>>(
            (const int4*)synidx, (const float4*)weights, (const int4*)synids,
            basis, (const ulonglong2*)mask, out, n_post, n_syn);
    }
}